// Round 1
// baseline (744.683 us; speedup 1.0000x reference)
//
#include <hip/hip_runtime.h>

// Problem constants (fixed by setup_inputs)
#define M_DIM 4096
#define K_DIM 4096
#define N_DIM 12288
// GEMM tile
#define BM 128
#define BN 128
#define BK 64

typedef __bf16 bf16x8 __attribute__((ext_vector_type(8)));
typedef float  floatx4 __attribute__((ext_vector_type(4)));

// ---------------- x fp32 -> bf16 ----------------
__global__ __launch_bounds__(256) void xcast_kernel(const float* __restrict__ x,
                                                    __bf16* __restrict__ xb) {
    int idx = blockIdx.x * 256 + threadIdx.x;      // each thread: 8 floats
    const float4* xv = (const float4*)x;
    float4 a = xv[idx * 2];
    float4 b = xv[idx * 2 + 1];
    bf16x8 o;
    o[0] = (__bf16)a.x; o[1] = (__bf16)a.y; o[2] = (__bf16)a.z; o[3] = (__bf16)a.w;
    o[4] = (__bf16)b.x; o[5] = (__bf16)b.y; o[6] = (__bf16)b.z; o[7] = (__bf16)b.w;
    ((bf16x8*)xb)[idx] = o;
}

// ---------------- W int4 -> bf16 dequant ----------------
// qweight: [N, K/2] int32, each element one byte; low nibble = even k, high = odd k.
// wscales/wzeros: [G, N], G = K/128. w = (nibble - z) * s.
__global__ __launch_bounds__(256) void dequant_kernel(const int* __restrict__ qw,
                                                      const float* __restrict__ scales,
                                                      const float* __restrict__ zeros,
                                                      __bf16* __restrict__ wb) {
    int idx = blockIdx.x * 256 + threadIdx.x;      // 0 .. N * (K/2/4)
    int n  = idx >> 9;                             // (K/2)/4 = 512 per row
    int jq = (idx & 511) << 2;                     // byte-column, step 4
    int g  = jq >> 6;                              // group = (2*j)/128 = j/64
    float s = scales[g * N_DIM + n];
    float z = zeros[g * N_DIM + n];
    int4 q = *(const int4*)(qw + (size_t)n * (K_DIM / 2) + jq);
    bf16x8 o;
    o[0] = (__bf16)(((float)(q.x & 15)        - z) * s);
    o[1] = (__bf16)(((float)((q.x >> 4) & 15) - z) * s);
    o[2] = (__bf16)(((float)(q.y & 15)        - z) * s);
    o[3] = (__bf16)(((float)((q.y >> 4) & 15) - z) * s);
    o[4] = (__bf16)(((float)(q.z & 15)        - z) * s);
    o[5] = (__bf16)(((float)((q.z >> 4) & 15) - z) * s);
    o[6] = (__bf16)(((float)(q.w & 15)        - z) * s);
    o[7] = (__bf16)(((float)((q.w >> 4) & 15) - z) * s);
    *(bf16x8*)(wb + (size_t)n * K_DIM + (size_t)jq * 2) = o;
}

// ---------------- bf16 GEMM: C[M,N] = A[M,K] * B[N,K]^T + bias ----------------
// m97 structure: 128x128 tile, BK=64, 4 waves each computing 64x64 via 4x4
// mfma_f32_16x16x32_bf16; global_load_lds width=16 staging; XOR-swizzled LDS
// k-block to kill ds_read_b128 bank conflicts.
__global__ __launch_bounds__(256, 2) void gemm_kernel(const __bf16* __restrict__ A,
                                                      const __bf16* __restrict__ B,
                                                      const float* __restrict__ bias,
                                                      float* __restrict__ C) {
    __shared__ __bf16 As[BM * BK];   // 16 KB
    __shared__ __bf16 Bs[BN * BK];   // 16 KB

    const int tid  = threadIdx.x;
    const int wave = tid >> 6;
    const int lane = tid & 63;
    const int quad = lane >> 4;
    const int l16  = lane & 15;
    const int wm = (wave >> 1) * 64;     // wave's m offset in tile
    const int wn = (wave & 1) * 64;      // wave's n offset in tile
    const int bm0 = blockIdx.y * BM;
    const int bn0 = blockIdx.x * BN;

    // Staging geometry: one global_load_lds covers 64 lanes x 16B = 8 rows of 64 bf16.
    // lane -> (rowInChunk = lane>>3, 16B-block). We XOR the k-block with the row so
    // that logical element (row, blk) lands at LDS offset row*64 + (blk^(row&7))*8.
    const int rowInChunk = lane >> 3;                 // 0..7
    const int kblk       = (lane & 7) ^ rowInChunk;   // swizzled 16B block index
    const int kOffElem   = kblk * 8;

    floatx4 acc[4][4] = {};

    for (int kt = 0; kt < K_DIM / BK; ++kt) {
        const int k0 = kt * BK;
        #pragma unroll
        for (int r = 0; r < 4; ++r) {
            const int chunk = wave * 4 + r;           // 16 chunks of 8 rows
            const int row   = chunk * 8 + rowInChunk;
            const __bf16* ga = A + (size_t)(bm0 + row) * K_DIM + k0 + kOffElem;
            const __bf16* gb = B + (size_t)(bn0 + row) * K_DIM + k0 + kOffElem;
            __builtin_amdgcn_global_load_lds(
                (const __attribute__((address_space(1))) void*)ga,
                (__attribute__((address_space(3))) void*)(As + chunk * 8 * BK), 16, 0, 0);
            __builtin_amdgcn_global_load_lds(
                (const __attribute__((address_space(1))) void*)gb,
                (__attribute__((address_space(3))) void*)(Bs + chunk * 8 * BK), 16, 0, 0);
        }
        __syncthreads();

        #pragma unroll
        for (int ks = 0; ks < 2; ++ks) {
            bf16x8 af[4], bfr[4];
            const int kx = (ks << 2) | quad;          // 16B-block index along BK
            #pragma unroll
            for (int i = 0; i < 4; ++i) {
                const int ar = wm + i * 16 + l16;     // A tile row (m)
                const int br = wn + i * 16 + l16;     // B tile row (n)
                af[i]  = *(const bf16x8*)(As + ar * BK + ((kx ^ (l16 & 7)) << 3));
                bfr[i] = *(const bf16x8*)(Bs + br * BK + ((kx ^ (l16 & 7)) << 3));
            }
            #pragma unroll
            for (int mi = 0; mi < 4; ++mi)
                #pragma unroll
                for (int ni = 0; ni < 4; ++ni)
                    acc[mi][ni] = __builtin_amdgcn_mfma_f32_16x16x32_bf16(
                        af[mi], bfr[ni], acc[mi][ni], 0, 0, 0);
        }
        __syncthreads();
    }

    // Epilogue: D element (m = quad*4 + reg, n = l16) per 16x16 tile; + bias; fp32 out.
    #pragma unroll
    for (int ni = 0; ni < 4; ++ni) {
        const int col = bn0 + wn + ni * 16 + l16;
        const float bv = bias[col];
        #pragma unroll
        for (int mi = 0; mi < 4; ++mi) {
            #pragma unroll
            for (int r = 0; r < 4; ++r) {
                const int row = bm0 + wm + mi * 16 + quad * 4 + r;
                C[(size_t)row * N_DIM + col] = acc[mi][ni][r] + bv;
            }
        }
    }
}

extern "C" void kernel_launch(void* const* d_in, const int* in_sizes, int n_in,
                              void* d_out, int out_size, void* d_ws, size_t ws_size,
                              hipStream_t stream) {
    const float* x      = (const float*)d_in[0];
    const int*   qw     = (const int*)d_in[1];
    const float* scales = (const float*)d_in[2];
    const float* zeros  = (const float*)d_in[3];
    const float* bias   = (const float*)d_in[4];
    float* out = (float*)d_out;

    // Workspace layout: [xb: M*K bf16 = 32 MiB][wb: N*K bf16 = 96 MiB] = 128 MiB
    __bf16* xb = (__bf16*)d_ws;
    __bf16* wb = (__bf16*)((char*)d_ws + (size_t)M_DIM * K_DIM * 2);

    xcast_kernel<<<(M_DIM * K_DIM / 8) / 256, 256, 0, stream>>>(x, xb);
    dequant_kernel<<<(N_DIM * (K_DIM / 2) / 4) / 256, 256, 0, stream>>>(qw, scales, zeros, wb);

    dim3 grid(N_DIM / BN, M_DIM / BM);   // (96, 32)
    gemm_kernel<<<grid, 256, 0, stream>>>(xb, wb, bias, out);
}

// Round 2
// 696.414 us; speedup vs baseline: 1.0693x; 1.0693x over previous
//
#include <hip/hip_runtime.h>

// Problem constants (fixed by setup_inputs)
#define M_DIM 4096
#define K_DIM 4096
#define N_DIM 12288
// GEMM tile
#define BM 128
#define BN 128
#define BK 64

typedef __bf16 bf16x8  __attribute__((ext_vector_type(8)));
typedef float  floatx16 __attribute__((ext_vector_type(16)));

// ---------------- x fp32 -> bf16 ----------------
__global__ __launch_bounds__(256) void xcast_kernel(const float* __restrict__ x,
                                                    __bf16* __restrict__ xb) {
    int idx = blockIdx.x * 256 + threadIdx.x;      // each thread: 8 floats
    const float4* xv = (const float4*)x;
    float4 a = xv[idx * 2];
    float4 b = xv[idx * 2 + 1];
    bf16x8 o;
    o[0] = (__bf16)a.x; o[1] = (__bf16)a.y; o[2] = (__bf16)a.z; o[3] = (__bf16)a.w;
    o[4] = (__bf16)b.x; o[5] = (__bf16)b.y; o[6] = (__bf16)b.z; o[7] = (__bf16)b.w;
    ((bf16x8*)xb)[idx] = o;
}

// ---------------- W int4 -> bf16 dequant ----------------
__global__ __launch_bounds__(256) void dequant_kernel(const int* __restrict__ qw,
                                                      const float* __restrict__ scales,
                                                      const float* __restrict__ zeros,
                                                      __bf16* __restrict__ wb) {
    int idx = blockIdx.x * 256 + threadIdx.x;      // 0 .. N * (K/2/4)
    int n  = idx >> 9;                             // (K/2)/4 = 512 per row
    int jq = (idx & 511) << 2;                     // int32-column, step 4
    int g  = jq >> 6;                              // group = (2*j)/128 = j/64
    float s = scales[g * N_DIM + n];
    float z = zeros[g * N_DIM + n];
    int4 q = *(const int4*)(qw + (size_t)n * (K_DIM / 2) + jq);
    bf16x8 o;
    o[0] = (__bf16)(((float)(q.x & 15)        - z) * s);
    o[1] = (__bf16)(((float)((q.x >> 4) & 15) - z) * s);
    o[2] = (__bf16)(((float)(q.y & 15)        - z) * s);
    o[3] = (__bf16)(((float)((q.y >> 4) & 15) - z) * s);
    o[4] = (__bf16)(((float)(q.z & 15)        - z) * s);
    o[5] = (__bf16)(((float)((q.z >> 4) & 15) - z) * s);
    o[6] = (__bf16)(((float)(q.w & 15)        - z) * s);
    o[7] = (__bf16)(((float)((q.w >> 4) & 15) - z) * s);
    *(bf16x8*)(wb + (size_t)n * K_DIM + (size_t)jq * 2) = o;
}

// ---------------- bf16 GEMM: C[M,N] = A[M,K] * B[N,K]^T + bias ----------------
// 128x128 tile, BK=64, 4 waves each computing 64x64 as 2x2 of
// mfma_f32_32x32x16_bf16 (2495 TF ubench vs 2075 for 16x16x32).
// global_load_lds width=16 staging; XOR-swizzled 16B k-block (conflict-free).
// grid.x = M-tiles so co-resident blocks share all of A (L3-resident).
__global__ __launch_bounds__(256, 2) void gemm_kernel(const __bf16* __restrict__ A,
                                                      const __bf16* __restrict__ B,
                                                      const float* __restrict__ bias,
                                                      float* __restrict__ C) {
    __shared__ __bf16 As[BM * BK];   // 16 KB
    __shared__ __bf16 Bs[BN * BK];   // 16 KB

    const int tid  = threadIdx.x;
    const int wave = tid >> 6;
    const int lane = tid & 63;
    const int l32  = lane & 31;
    const int half = lane >> 5;
    const int wm = (wave >> 1) * 64;     // wave's m offset in tile
    const int wn = (wave & 1) * 64;      // wave's n offset in tile
    const int bm0 = blockIdx.x * BM;     // x = M tiles (32): consecutive blocks
    const int bn0 = blockIdx.y * BN;     // share one B tile, cover all of A

    // Staging: one global_load_lds = 64 lanes x 16B = 8 rows x 64 bf16.
    // Logical element (row, blk) lands at LDS row*64 + (blk^(row&7))*8.
    const int rowInChunk = lane >> 3;                 // 0..7
    const int kblk       = (lane & 7) ^ rowInChunk;   // swizzled 16B block index
    const int kOffElem   = kblk * 8;

    floatx16 acc[2][2] = {};

    for (int kt = 0; kt < K_DIM / BK; ++kt) {
        const int k0 = kt * BK;
        #pragma unroll
        for (int r = 0; r < 4; ++r) {
            const int chunk = wave * 4 + r;           // 16 chunks of 8 rows
            const int row   = chunk * 8 + rowInChunk;
            const __bf16* ga = A + (size_t)(bm0 + row) * K_DIM + k0 + kOffElem;
            const __bf16* gb = B + (size_t)(bn0 + row) * K_DIM + k0 + kOffElem;
            __builtin_amdgcn_global_load_lds(
                (const __attribute__((address_space(1))) void*)ga,
                (__attribute__((address_space(3))) void*)(As + chunk * 8 * BK), 16, 0, 0);
            __builtin_amdgcn_global_load_lds(
                (const __attribute__((address_space(1))) void*)gb,
                (__attribute__((address_space(3))) void*)(Bs + chunk * 8 * BK), 16, 0, 0);
        }
        __syncthreads();

        #pragma unroll
        for (int ks = 0; ks < 4; ++ks) {              // 4 k-steps of 16
            bf16x8 af[2], bfr[2];
            const int blk = ks * 2 + half;            // 16B-block along BK
            #pragma unroll
            for (int t = 0; t < 2; ++t) {
                const int ra = wm + t * 32 + l32;     // A tile row (m)
                const int rb = wn + t * 32 + l32;     // B tile row (n)
                af[t]  = *(const bf16x8*)(As + ra * BK + ((blk ^ (ra & 7)) << 3));
                bfr[t] = *(const bf16x8*)(Bs + rb * BK + ((blk ^ (rb & 7)) << 3));
            }
            #pragma unroll
            for (int mi = 0; mi < 2; ++mi)
                #pragma unroll
                for (int ni = 0; ni < 2; ++ni)
                    acc[mi][ni] = __builtin_amdgcn_mfma_f32_32x32x16_bf16(
                        af[mi], bfr[ni], acc[mi][ni], 0, 0, 0);
        }
        __syncthreads();
    }

    // Epilogue: 32x32 C/D layout: col = lane&31, row = (reg&3)+8*(reg>>2)+4*half.
    #pragma unroll
    for (int ni = 0; ni < 2; ++ni) {
        const int col = bn0 + wn + ni * 32 + l32;
        const float bv = bias[col];
        #pragma unroll
        for (int mi = 0; mi < 2; ++mi) {
            #pragma unroll
            for (int reg = 0; reg < 16; ++reg) {
                const int row = bm0 + wm + mi * 32 + half * 4 + (reg & 3) + 8 * (reg >> 2);
                C[(size_t)row * N_DIM + col] = acc[mi][ni][reg] + bv;
            }
        }
    }
}

extern "C" void kernel_launch(void* const* d_in, const int* in_sizes, int n_in,
                              void* d_out, int out_size, void* d_ws, size_t ws_size,
                              hipStream_t stream) {
    const float* x      = (const float*)d_in[0];
    const int*   qw     = (const int*)d_in[1];
    const float* scales = (const float*)d_in[2];
    const float* zeros  = (const float*)d_in[3];
    const float* bias   = (const float*)d_in[4];
    float* out = (float*)d_out;

    // Workspace layout: [xb: M*K bf16 = 32 MiB][wb: N*K bf16 = 96 MiB] = 128 MiB
    __bf16* xb = (__bf16*)d_ws;
    __bf16* wb = (__bf16*)((char*)d_ws + (size_t)M_DIM * K_DIM * 2);

    xcast_kernel<<<(M_DIM * K_DIM / 8) / 256, 256, 0, stream>>>(x, xb);
    dequant_kernel<<<(N_DIM * (K_DIM / 2) / 4) / 256, 256, 0, stream>>>(qw, scales, zeros, wb);

    dim3 grid(M_DIM / BM, N_DIM / BN);   // (32, 96): x = M tiles
    gemm_kernel<<<grid, 256, 0, stream>>>(xb, wb, bias, out);
}

// Round 3
// 692.256 us; speedup vs baseline: 1.0757x; 1.0060x over previous
//
#include <hip/hip_runtime.h>

// Problem constants (fixed by setup_inputs)
#define M_DIM 4096
#define K_DIM 4096
#define N_DIM 12288
// GEMM tile
#define BM 256
#define BN 128
#define BK 64

typedef __bf16 bf16x8  __attribute__((ext_vector_type(8)));
typedef float  floatx16 __attribute__((ext_vector_type(16)));

// ---------------- x fp32 -> bf16 ----------------
__global__ __launch_bounds__(256) void xcast_kernel(const float* __restrict__ x,
                                                    __bf16* __restrict__ xb) {
    int idx = blockIdx.x * 256 + threadIdx.x;      // each thread: 8 floats
    const float4* xv = (const float4*)x;
    float4 a = xv[idx * 2];
    float4 b = xv[idx * 2 + 1];
    bf16x8 o;
    o[0] = (__bf16)a.x; o[1] = (__bf16)a.y; o[2] = (__bf16)a.z; o[3] = (__bf16)a.w;
    o[4] = (__bf16)b.x; o[5] = (__bf16)b.y; o[6] = (__bf16)b.z; o[7] = (__bf16)b.w;
    ((bf16x8*)xb)[idx] = o;
}

// ---------------- W int4 -> bf16 dequant ----------------
__global__ __launch_bounds__(256) void dequant_kernel(const int* __restrict__ qw,
                                                      const float* __restrict__ scales,
                                                      const float* __restrict__ zeros,
                                                      __bf16* __restrict__ wb) {
    int idx = blockIdx.x * 256 + threadIdx.x;      // 0 .. N * (K/2/4)
    int n  = idx >> 9;                             // (K/2)/4 = 512 per row
    int jq = (idx & 511) << 2;                     // int32-column, step 4
    int g  = jq >> 6;                              // group = (2*j)/128 = j/64
    float s = scales[g * N_DIM + n];
    float z = zeros[g * N_DIM + n];
    int4 q = *(const int4*)(qw + (size_t)n * (K_DIM / 2) + jq);
    bf16x8 o;
    o[0] = (__bf16)(((float)(q.x & 15)        - z) * s);
    o[1] = (__bf16)(((float)((q.x >> 4) & 15) - z) * s);
    o[2] = (__bf16)(((float)(q.y & 15)        - z) * s);
    o[3] = (__bf16)(((float)((q.y >> 4) & 15) - z) * s);
    o[4] = (__bf16)(((float)(q.z & 15)        - z) * s);
    o[5] = (__bf16)(((float)((q.z >> 4) & 15) - z) * s);
    o[6] = (__bf16)(((float)(q.w & 15)        - z) * s);
    o[7] = (__bf16)(((float)((q.w >> 4) & 15) - z) * s);
    *(bf16x8*)(wb + (size_t)n * K_DIM + (size_t)jq * 2) = o;
}

// ---------------- bf16 GEMM: C[M,N] = A[M,K] * B[N,K]^T + bias ----------------
// 256x128 block tile, BK=64; 4 waves each 128x64 via 4x2 of
// mfma_f32_32x32x16_bf16 -> 43.7 FLOP per LDS byte (was 32).
// Swizzle g(row) = (row&7) ^ (((row>>3)&3)<<1): conflict-free under both
// consecutive-8 and stride-8 LDS phase groupings (round-2 counter evidence
// showed stride-8 grouping: 5e7 conflicts from a row&7-only key).
__global__ __launch_bounds__(256, 2) void gemm_kernel(const __bf16* __restrict__ A,
                                                      const __bf16* __restrict__ B,
                                                      const float* __restrict__ bias,
                                                      float* __restrict__ C) {
    __shared__ __bf16 As[BM * BK];   // 32 KB
    __shared__ __bf16 Bs[BN * BK];   // 16 KB

    const int tid  = threadIdx.x;
    const int wave = tid >> 6;
    const int lane = tid & 63;
    const int l32  = lane & 31;
    const int half = lane >> 5;
    const int wm = (wave >> 1) * 128;    // wave's m offset in tile (0 or 128)
    const int wn = (wave & 1) * 64;      // wave's n offset in tile (0 or 64)
    const int bm0 = blockIdx.x * BM;     // x = M tiles: consecutive blocks share B
    const int bn0 = blockIdx.y * BN;

    // Staging: one global_load_lds = 64 lanes x 16B = 8 rows x 64 bf16.
    // Logical element (row, blk) lands at LDS row*64 + (blk ^ g(row))*8,
    // g(row) = (row&7) ^ (((row>>3)&3)<<1).
    const int rowInChunk = lane >> 3;                 // 0..7
    const int slot       = lane & 7;

    // Per-lane read swizzle key: for fragment rows ra = base32 + l32 with
    // base32 % 32 == 0, g(ra) = (l32&7) ^ (((l32>>3)&3)<<1).
    const int gread = (l32 & 7) ^ (((l32 >> 3) & 3) << 1);

    floatx16 acc[4][2] = {};

    for (int kt = 0; kt < K_DIM / BK; ++kt) {
        const int k0 = kt * BK;
        // A: 32 chunks of 8 rows; 8 per wave
        #pragma unroll
        for (int r = 0; r < 8; ++r) {
            const int chunk = wave * 8 + r;
            const int row   = chunk * 8 + rowInChunk;
            const int kblk  = slot ^ rowInChunk ^ ((r & 3) << 1);  // (chunk&3)==r&3
            const __bf16* ga = A + (size_t)(bm0 + row) * K_DIM + k0 + kblk * 8;
            __builtin_amdgcn_global_load_lds(
                (const __attribute__((address_space(1))) void*)ga,
                (__attribute__((address_space(3))) void*)(As + chunk * 512), 16, 0, 0);
        }
        // B: 16 chunks of 8 rows; 4 per wave
        #pragma unroll
        for (int r = 0; r < 4; ++r) {
            const int chunk = wave * 4 + r;
            const int row   = chunk * 8 + rowInChunk;
            const int kblk  = slot ^ rowInChunk ^ ((r & 3) << 1);
            const __bf16* gb = B + (size_t)(bn0 + row) * K_DIM + k0 + kblk * 8;
            __builtin_amdgcn_global_load_lds(
                (const __attribute__((address_space(1))) void*)gb,
                (__attribute__((address_space(3))) void*)(Bs + chunk * 512), 16, 0, 0);
        }
        __syncthreads();

        #pragma unroll
        for (int ks = 0; ks < 4; ++ks) {              // 4 k-steps of 16
            const int blk = ks * 2 + half;            // logical 16B-block along BK
            const int off = (blk ^ gread) << 3;       // swizzled element offset
            bf16x8 af[4], bfr[2];
            #pragma unroll
            for (int i = 0; i < 4; ++i)
                af[i] = *(const bf16x8*)(As + (wm + i * 32 + l32) * BK + off);
            #pragma unroll
            for (int t = 0; t < 2; ++t)
                bfr[t] = *(const bf16x8*)(Bs + (wn + t * 32 + l32) * BK + off);
            #pragma unroll
            for (int mi = 0; mi < 4; ++mi)
                #pragma unroll
                for (int ni = 0; ni < 2; ++ni)
                    acc[mi][ni] = __builtin_amdgcn_mfma_f32_32x32x16_bf16(
                        af[mi], bfr[ni], acc[mi][ni], 0, 0, 0);
        }
        __syncthreads();
    }

    // Epilogue: 32x32 C/D layout: col = lane&31, row = (reg&3)+8*(reg>>2)+4*half.
    #pragma unroll
    for (int ni = 0; ni < 2; ++ni) {
        const int col = bn0 + wn + ni * 32 + l32;
        const float bv = bias[col];
        #pragma unroll
        for (int mi = 0; mi < 4; ++mi) {
            #pragma unroll
            for (int reg = 0; reg < 16; ++reg) {
                const int row = bm0 + wm + mi * 32 + half * 4 + (reg & 3) + 8 * (reg >> 2);
                C[(size_t)row * N_DIM + col] = acc[mi][ni][reg] + bv;
            }
        }
    }
}

extern "C" void kernel_launch(void* const* d_in, const int* in_sizes, int n_in,
                              void* d_out, int out_size, void* d_ws, size_t ws_size,
                              hipStream_t stream) {
    const float* x      = (const float*)d_in[0];
    const int*   qw     = (const int*)d_in[1];
    const float* scales = (const float*)d_in[2];
    const float* zeros  = (const float*)d_in[3];
    const float* bias   = (const float*)d_in[4];
    float* out = (float*)d_out;

    // Workspace layout: [xb: M*K bf16 = 32 MiB][wb: N*K bf16 = 96 MiB] = 128 MiB
    __bf16* xb = (__bf16*)d_ws;
    __bf16* wb = (__bf16*)((char*)d_ws + (size_t)M_DIM * K_DIM * 2);

    xcast_kernel<<<(M_DIM * K_DIM / 8) / 256, 256, 0, stream>>>(x, xb);
    dequant_kernel<<<(N_DIM * (K_DIM / 2) / 4) / 256, 256, 0, stream>>>(qw, scales, zeros, wb);

    dim3 grid(M_DIM / BM, N_DIM / BN);   // (16, 96): x = M tiles
    gemm_kernel<<<grid, 256, 0, stream>>>(xb, wb, bias, out);
}